// Round 2
// baseline (134.018 us; speedup 1.0000x reference)
//
#include <hip/hip_runtime.h>
#include <math.h>

// Problem constants (from setup_inputs): x[B,D] fp32, K=8 bins per column.
#define DD   256
#define KK   8
#define DTILE 64      // d-columns per block
#define ROWS  128     // b-rows per block

// ---------------------------------------------------------------------------
// Setup kernel: one thread per column d. Computes, per sub-bin j in [0,16):
//   out(x) = (A' + B'x) / (C' + D'x)   for x in [s[j], s[j+1])
// where sub-bin 2k is theta in [0,lam_k], 2k+1 is theta in [lam_k,1].
// Coefficients composed in double to avoid cancellation when 1/width is big.
// parG: float4[D*16]  (A',B',C',D') per (d, sub-bin)
// bndG: float [D*15]  interior boundaries s[1..15] per d (s[0]=-3, s[16]=3+eps
//                     are never probed by the search)
// ---------------------------------------------------------------------------
__global__ void spline_setup(const float* __restrict__ uw, const float* __restrict__ uh,
                             const float* __restrict__ ud, const float* __restrict__ ul,
                             float4* __restrict__ parG, float* __restrict__ bndG) {
    int d = blockIdx.x * blockDim.x + threadIdx.x;
    if (d >= DD) return;
    const float* uwd = uw + d * KK;
    const float* uhd = uh + d * KK;
    const float* udd = ud + d * (KK - 1);
    const float* uld = ul + d * KK;

    // softmax (match reference: max-subtracted fp32 exp)
    float mw = -1e30f, mh = -1e30f;
    for (int k = 0; k < KK; ++k) { mw = fmaxf(mw, uwd[k]); mh = fmaxf(mh, uhd[k]); }
    double sw = 0.0, sh = 0.0;
    for (int k = 0; k < KK; ++k) { sw += (double)expf(uwd[k] - mw); sh += (double)expf(uhd[k] - mh); }
    double invsw = 1.0 / sw, invsh = 1.0 / sh;

    double kx[KK + 1], ky[KK + 1], der[KK + 1], lam[KK];
    double cw = 0.0, ch = 0.0;
    kx[0] = -3.0; ky[0] = -3.0;
    for (int k = 0; k < KK; ++k) {
        double wk = 1e-3 + (1.0 - 1e-3 * KK) * ((double)expf(uwd[k] - mw) * invsw);
        double hk = 1e-3 + (1.0 - 1e-3 * KK) * ((double)expf(uhd[k] - mh) * invsh);
        cw += wk; ch += hk;
        kx[k + 1] = 6.0 * cw - 3.0;
        ky[k + 1] = 6.0 * ch - 3.0;
    }
    kx[KK] = 3.0; ky[KK] = 3.0;   // reference forces endpoints before taking diffs
    der[0] = 1.0 - 1e-3; der[KK] = 1.0 - 1e-3;   // pad value 1.0 - MIN_DERIV
    for (int k = 0; k < KK - 1; ++k)
        der[k + 1] = 1e-3 + (double)log1pf(expf(udd[k]));     // MIN_DERIV + softplus
    for (int k = 0; k < KK; ++k)
        lam[k] = 0.025 + 0.95 * (1.0 / (1.0 + (double)expf(-uld[k])));

    for (int k = 0; k < KK; ++k) {
        double wdt = kx[k + 1] - kx[k];
        double hgt = ky[k + 1] - ky[k];
        double d0 = der[k], d1 = der[k + 1], l = lam[k];
        double delta = hgt / wdt;
        double wb = sqrt(d0 / d1);                       // wa = 1
        double wc = (l * d0 + (1.0 - l) * wb * d1) / delta;
        double ya = ky[k], yb = ky[k] + hgt;
        double wcyc = wc * (((1.0 - l) * ya + l * wb * yb) / ((1.0 - l) + l * wb));
        double wbyb = wb * yb;
        double invw = 1.0 / wdt, icw = kx[k];

        // left sub-bin (theta <= l):  num = ya*l + (wcyc-ya)*th ; den = l + (wc-1)*th
        {
            double A = ya * l, P = wcyc - ya, C = l, Q = wc - 1.0;
            double Bp = P * invw, Dp = Q * invw;
            parG[d * 16 + 2 * k] = make_float4((float)(A - Bp * icw), (float)Bp,
                                               (float)(C - Dp * icw), (float)Dp);
        }
        // right sub-bin: num = (wcyc - wbyb*l) + (wbyb-wcyc)*th ; den = (wc - wb*l) + (wb-wc)*th
        {
            double A = wcyc - wbyb * l, P = wbyb - wcyc, C = wc - wb * l, Q = wb - wc;
            double Bp = P * invw, Dp = Q * invw;
            parG[d * 16 + 2 * k + 1] = make_float4((float)(A - Bp * icw), (float)Bp,
                                                   (float)(C - Dp * icw), (float)Dp);
        }
        // boundaries: s[2k]=kx[k], s[2k+1]=kx[k]+l*wdt ; store s[1..15] at [i-1]
        if (k > 0) bndG[d * 15 + (2 * k - 1)] = (float)kx[k];
        bndG[d * 15 + (2 * k)]     = (float)(kx[k] + l * wdt);
    }
}

// ---------------------------------------------------------------------------
// Main kernel: block = 4 waves x 64 lanes. lane -> d within a 64-wide d-tile,
// wave -> row group. The 15 bin boundaries are per-COLUMN constants, and each
// thread owns one column for its whole row range -> hoist boundaries into 15
// VGPRs once; per-element bin search is a pure-VALU cndmask tree (no LDS).
// Only remaining per-element LDS op: one ds_read_b128 for the Mobius coeffs
// (stride 17 float4 = 68 floats; b128's 8-phase processing is the floor).
// ---------------------------------------------------------------------------
__global__ __launch_bounds__(256, 4)
void spline_main(const float* __restrict__ x, const float4* __restrict__ parG,
                 const float* __restrict__ bndG, float* __restrict__ out, int B) {
    __shared__ float4 s_par[DTILE * 17];
    __shared__ float  s_bnd[DTILE * 15];

    const int tid = threadIdx.x;
    const int dbase = blockIdx.x * DTILE;

    for (int i = tid; i < DTILE * 16; i += 256) {
        int ld = i >> 4, j = i & 15;
        s_par[ld * 17 + j] = parG[(size_t)(dbase + ld) * 16 + j];
    }
    for (int i = tid; i < DTILE * 15; i += 256) {
        s_bnd[i] = bndG[(size_t)dbase * 15 + i];   // contiguous slab for the tile
    }
    __syncthreads();

    const int lane = tid & 63;
    const int w    = tid >> 6;
    const int d    = dbase + lane;
    const size_t rowbase = (size_t)(blockIdx.y * ROWS + w * (ROWS / 4)) * DD + d;
    const float* xp = x + rowbase;
    float*       op = out + rowbase;
    const int pb = lane * 17;

    // hoist the column's 15 interior boundaries into registers (loop-invariant)
    const float* bl = &s_bnd[lane * 15];
    const float b1 = bl[0],  b2 = bl[1],  b3 = bl[2],  b4 = bl[3];
    const float b5 = bl[4],  b6 = bl[5],  b7 = bl[6],  b8 = bl[7];
    const float b9 = bl[8],  b10 = bl[9], b11 = bl[10], b12 = bl[11];
    const float b13 = bl[12], b14 = bl[13], b15 = bl[14];

    for (int it = 0; it < (ROWS / 4) / 4; ++it) {
        float xv[4];
#pragma unroll
        for (int r = 0; r < 4; ++r) xv[r] = xp[(size_t)(it * 4 + r) * DD];
#pragma unroll
        for (int r = 0; r < 4; ++r) {
            const float xo = xv[r];
            const float xc = fminf(fmaxf(xo, -3.0f), 3.0f);
            // 4-level branchless binary search over registers
            const bool c3 = xc >= b8;
            const float m2 = c3 ? b12 : b4;
            const bool c2 = xc >= m2;
            const float m1 = c3 ? (c2 ? b14 : b10) : (c2 ? b6 : b2);
            const bool c1 = xc >= m1;
            const float t01 = c1 ? b3  : b1;
            const float t23 = c1 ? b7  : b5;
            const float t45 = c1 ? b11 : b9;
            const float t67 = c1 ? b15 : b13;
            const float m0 = c3 ? (c2 ? t67 : t45) : (c2 ? t23 : t01);
            const bool c0 = xc >= m0;
            const int j = (c3 ? 8 : 0) + (c2 ? 4 : 0) + (c1 ? 2 : 0) + (c0 ? 1 : 0);

            const float4 p = s_par[pb + j];
            const float num = fmaf(p.y, xc, p.x);
            const float den = fmaf(p.w, xc, p.z);
            const float res = __fdividef(num, den);
            const bool inside = (xo >= -3.0f) && (xo <= 3.0f);
            op[(size_t)(it * 4 + r) * DD] = inside ? res : xo;
        }
    }
}

extern "C" void kernel_launch(void* const* d_in, const int* in_sizes, int n_in,
                              void* d_out, int out_size, void* d_ws, size_t ws_size,
                              hipStream_t stream) {
    const float* x  = (const float*)d_in[0];
    const float* uw = (const float*)d_in[1];
    const float* uh = (const float*)d_in[2];
    const float* ud = (const float*)d_in[3];
    const float* ul = (const float*)d_in[4];
    float* outp = (float*)d_out;

    const int B = in_sizes[0] / DD;   // 65536

    float4* parG = (float4*)d_ws;                                  // 256*16*16 = 64 KiB
    float*  bndG = (float*)((char*)d_ws + (size_t)DD * 16 * sizeof(float4)); // +15 KiB

    spline_setup<<<dim3((DD + 63) / 64), dim3(64), 0, stream>>>(uw, uh, ud, ul, parG, bndG);
    spline_main<<<dim3(DD / DTILE, B / ROWS), dim3(256), 0, stream>>>(x, parG, bndG, outp, B);
}

// Round 3
// 130.646 us; speedup vs baseline: 1.0258x; 1.0258x over previous
//
#include <hip/hip_runtime.h>
#include <math.h>

// Problem constants (from setup_inputs): x[B,D] fp32, K=8 bins per column.
#define DD   256
#define KK   8
#define DTILE 64      // d-columns per block
#define ROWS  128     // b-rows per block (32 per wave)

// ---------------------------------------------------------------------------
// Setup kernel: one thread per column d. Computes, per sub-bin j in [0,16):
//   out(x) = (A' + B'x) / (C' + D'x)   for x in [s[j], s[j+1])
// where sub-bin 2k is theta in [0,lam_k], 2k+1 is theta in [lam_k,1].
// Coefficients composed in double to avoid cancellation when 1/width is big.
// parG: float4[D*16]  (A',B',C',D') per (d, sub-bin)
// bndG: float [D*15]  interior boundaries s[1..15] per d
// ---------------------------------------------------------------------------
__global__ void spline_setup(const float* __restrict__ uw, const float* __restrict__ uh,
                             const float* __restrict__ ud, const float* __restrict__ ul,
                             float4* __restrict__ parG, float* __restrict__ bndG) {
    int d = blockIdx.x * blockDim.x + threadIdx.x;
    if (d >= DD) return;
    const float* uwd = uw + d * KK;
    const float* uhd = uh + d * KK;
    const float* udd = ud + d * (KK - 1);
    const float* uld = ul + d * KK;

    // softmax (match reference: max-subtracted fp32 exp)
    float mw = -1e30f, mh = -1e30f;
    for (int k = 0; k < KK; ++k) { mw = fmaxf(mw, uwd[k]); mh = fmaxf(mh, uhd[k]); }
    double sw = 0.0, sh = 0.0;
    for (int k = 0; k < KK; ++k) { sw += (double)expf(uwd[k] - mw); sh += (double)expf(uhd[k] - mh); }
    double invsw = 1.0 / sw, invsh = 1.0 / sh;

    double kx[KK + 1], ky[KK + 1], der[KK + 1], lam[KK];
    double cw = 0.0, ch = 0.0;
    kx[0] = -3.0; ky[0] = -3.0;
    for (int k = 0; k < KK; ++k) {
        double wk = 1e-3 + (1.0 - 1e-3 * KK) * ((double)expf(uwd[k] - mw) * invsw);
        double hk = 1e-3 + (1.0 - 1e-3 * KK) * ((double)expf(uhd[k] - mh) * invsh);
        cw += wk; ch += hk;
        kx[k + 1] = 6.0 * cw - 3.0;
        ky[k + 1] = 6.0 * ch - 3.0;
    }
    kx[KK] = 3.0; ky[KK] = 3.0;   // reference forces endpoints before taking diffs
    der[0] = 1.0 - 1e-3; der[KK] = 1.0 - 1e-3;   // pad value 1.0 - MIN_DERIV
    for (int k = 0; k < KK - 1; ++k)
        der[k + 1] = 1e-3 + (double)log1pf(expf(udd[k]));     // MIN_DERIV + softplus
    for (int k = 0; k < KK; ++k)
        lam[k] = 0.025 + 0.95 * (1.0 / (1.0 + (double)expf(-uld[k])));

    for (int k = 0; k < KK; ++k) {
        double wdt = kx[k + 1] - kx[k];
        double hgt = ky[k + 1] - ky[k];
        double d0 = der[k], d1 = der[k + 1], l = lam[k];
        double delta = hgt / wdt;
        double wb = sqrt(d0 / d1);                       // wa = 1
        double wc = (l * d0 + (1.0 - l) * wb * d1) / delta;
        double ya = ky[k], yb = ky[k] + hgt;
        double wcyc = wc * (((1.0 - l) * ya + l * wb * yb) / ((1.0 - l) + l * wb));
        double wbyb = wb * yb;
        double invw = 1.0 / wdt, icw = kx[k];

        // left sub-bin (theta <= l):  num = ya*l + (wcyc-ya)*th ; den = l + (wc-1)*th
        {
            double A = ya * l, P = wcyc - ya, C = l, Q = wc - 1.0;
            double Bp = P * invw, Dp = Q * invw;
            parG[d * 16 + 2 * k] = make_float4((float)(A - Bp * icw), (float)Bp,
                                               (float)(C - Dp * icw), (float)Dp);
        }
        // right sub-bin: num = (wcyc - wbyb*l) + (wbyb-wcyc)*th ; den = (wc - wb*l) + (wb-wc)*th
        {
            double A = wcyc - wbyb * l, P = wbyb - wcyc, C = wc - wb * l, Q = wb - wc;
            double Bp = P * invw, Dp = Q * invw;
            parG[d * 16 + 2 * k + 1] = make_float4((float)(A - Bp * icw), (float)Bp,
                                                   (float)(C - Dp * icw), (float)Dp);
        }
        // boundaries: s[2k]=kx[k], s[2k+1]=kx[k]+l*wdt ; store s[1..15] at [i-1]
        if (k > 0) bndG[d * 15 + (2 * k - 1)] = (float)kx[k];
        bndG[d * 15 + (2 * k)]     = (float)(kx[k] + l * wdt);
    }
}

// ---------------------------------------------------------------------------
// Main kernel. lane -> one d-column; 15 boundaries live in VGPRs (loaded
// straight from global -> no s_bnd in LDS -> 17408 B LDS -> 8 blocks/CU).
// Latency hiding: rows processed in groups of 8 with next-group prefetch
// (steady state 8-16 loads in flight per thread).
// Bank-conflict fix: par slot swizzled by (lane>>3) so the 8 lanes sharing a
// mod-8 bank class rotate across the 8 bank-groups even when their data-
// dependent bin indices j coincide.
// ---------------------------------------------------------------------------
__global__ __launch_bounds__(256, 8)
void spline_main(const float* __restrict__ x, const float4* __restrict__ parG,
                 const float* __restrict__ bndG, float* __restrict__ out, int B) {
    __shared__ float4 s_par[DTILE * 17];   // stride 17 float4; slot 16 is pad

    const int tid = threadIdx.x;
    const int dbase = blockIdx.x * DTILE;
    const int lane = tid & 63;
    const int w    = tid >> 6;
    const int d    = dbase + lane;

    // start boundary loads early (independent of LDS staging)
    const float* bp = bndG + (size_t)d * 15;
    const float b1 = bp[0],  b2 = bp[1],  b3 = bp[2],  b4 = bp[3];
    const float b5 = bp[4],  b6 = bp[5],  b7 = bp[6],  b8 = bp[7];
    const float b9 = bp[8],  b10 = bp[9], b11 = bp[10], b12 = bp[11];
    const float b13 = bp[12], b14 = bp[13], b15 = bp[14];

    for (int i = tid; i < DTILE * 16; i += 256) {
        int ld = i >> 4, v = i & 15;
        s_par[ld * 17 + ((v + (ld >> 3)) & 15)] = parG[(size_t)(dbase + ld) * 16 + v];
    }
    __syncthreads();

    const size_t rowbase = (size_t)(blockIdx.y * ROWS + w * (ROWS / 4)) * DD + d;
    const float* xp = x + rowbase;
    float*       op = out + rowbase;
    const int pb  = lane * 17;
    const int rot = lane >> 3;

    float cur[8], nxt[8];
#pragma unroll
    for (int r = 0; r < 8; ++r) cur[r] = xp[(size_t)r * DD];

#pragma unroll 1
    for (int g = 0; g < 4; ++g) {
        if (g < 3) {
#pragma unroll
            for (int r = 0; r < 8; ++r) nxt[r] = xp[(size_t)((g + 1) * 8 + r) * DD];
        }
#pragma unroll
        for (int r = 0; r < 8; ++r) {
            const float xo = cur[r];
            const float xc = fminf(fmaxf(xo, -3.0f), 3.0f);
            // 4-level branchless binary search over registers
            const bool c3 = xc >= b8;
            const float m2 = c3 ? b12 : b4;
            const bool c2 = xc >= m2;
            const float m1 = c3 ? (c2 ? b14 : b10) : (c2 ? b6 : b2);
            const bool c1 = xc >= m1;
            const float t01 = c1 ? b3  : b1;
            const float t23 = c1 ? b7  : b5;
            const float t45 = c1 ? b11 : b9;
            const float t67 = c1 ? b15 : b13;
            const float m0 = c3 ? (c2 ? t67 : t45) : (c2 ? t23 : t01);
            const bool c0 = xc >= m0;
            const int j = (c3 ? 8 : 0) + (c2 ? 4 : 0) + (c1 ? 2 : 0) + (c0 ? 1 : 0);

            const float4 p = s_par[pb + ((j + rot) & 15)];
            const float num = fmaf(p.y, xc, p.x);
            const float den = fmaf(p.w, xc, p.z);
            const float res = __fdividef(num, den);
            const float val = (xo == xc) ? res : xo;   // outside [-3,3] -> identity
            __builtin_nontemporal_store(val, &op[(size_t)(g * 8 + r) * DD]);
        }
#pragma unroll
        for (int r = 0; r < 8; ++r) cur[r] = nxt[r];
    }
}

extern "C" void kernel_launch(void* const* d_in, const int* in_sizes, int n_in,
                              void* d_out, int out_size, void* d_ws, size_t ws_size,
                              hipStream_t stream) {
    const float* x  = (const float*)d_in[0];
    const float* uw = (const float*)d_in[1];
    const float* uh = (const float*)d_in[2];
    const float* ud = (const float*)d_in[3];
    const float* ul = (const float*)d_in[4];
    float* outp = (float*)d_out;

    const int B = in_sizes[0] / DD;   // 65536

    float4* parG = (float4*)d_ws;                                  // 256*16*16 = 64 KiB
    float*  bndG = (float*)((char*)d_ws + (size_t)DD * 16 * sizeof(float4)); // +15 KiB

    spline_setup<<<dim3((DD + 63) / 64), dim3(64), 0, stream>>>(uw, uh, ud, ul, parG, bndG);
    spline_main<<<dim3(DD / DTILE, B / ROWS), dim3(256), 0, stream>>>(x, parG, bndG, outp, B);
}

// Round 4
// 130.086 us; speedup vs baseline: 1.0302x; 1.0043x over previous
//
#include <hip/hip_runtime.h>
#include <math.h>

// Problem constants (from setup_inputs): x[B,D] fp32, K=8 bins per column.
#define DD   256
#define KK   8
#define DTILE 64      // d-columns per block
#define ROWS  128     // b-rows per block (32 per wave)

// ---------------------------------------------------------------------------
// Setup kernel: one thread per column d. Computes, per sub-bin j in [0,16):
//   out(x) = (A' + B'x) / (C' + D'x)   for x in [s[j], s[j+1])
// where sub-bin 2k is theta in [0,lam_k], 2k+1 is theta in [lam_k,1].
// Coefficients composed in double to avoid cancellation when 1/width is big.
// parG: float4[D*16]  (A',B',C',D') per (d, sub-bin)
// bndG: float [D*15]  interior boundaries s[1..15] per d
// ---------------------------------------------------------------------------
__global__ void spline_setup(const float* __restrict__ uw, const float* __restrict__ uh,
                             const float* __restrict__ ud, const float* __restrict__ ul,
                             float4* __restrict__ parG, float* __restrict__ bndG) {
    int d = blockIdx.x * blockDim.x + threadIdx.x;
    if (d >= DD) return;
    const float* uwd = uw + d * KK;
    const float* uhd = uh + d * KK;
    const float* udd = ud + d * (KK - 1);
    const float* uld = ul + d * KK;

    // softmax (match reference: max-subtracted fp32 exp)
    float mw = -1e30f, mh = -1e30f;
    for (int k = 0; k < KK; ++k) { mw = fmaxf(mw, uwd[k]); mh = fmaxf(mh, uhd[k]); }
    double sw = 0.0, sh = 0.0;
    for (int k = 0; k < KK; ++k) { sw += (double)expf(uwd[k] - mw); sh += (double)expf(uhd[k] - mh); }
    double invsw = 1.0 / sw, invsh = 1.0 / sh;

    double kx[KK + 1], ky[KK + 1], der[KK + 1], lam[KK];
    double cw = 0.0, ch = 0.0;
    kx[0] = -3.0; ky[0] = -3.0;
    for (int k = 0; k < KK; ++k) {
        double wk = 1e-3 + (1.0 - 1e-3 * KK) * ((double)expf(uwd[k] - mw) * invsw);
        double hk = 1e-3 + (1.0 - 1e-3 * KK) * ((double)expf(uhd[k] - mh) * invsh);
        cw += wk; ch += hk;
        kx[k + 1] = 6.0 * cw - 3.0;
        ky[k + 1] = 6.0 * ch - 3.0;
    }
    kx[KK] = 3.0; ky[KK] = 3.0;   // reference forces endpoints before taking diffs
    der[0] = 1.0 - 1e-3; der[KK] = 1.0 - 1e-3;   // pad value 1.0 - MIN_DERIV
    for (int k = 0; k < KK - 1; ++k)
        der[k + 1] = 1e-3 + (double)log1pf(expf(udd[k]));     // MIN_DERIV + softplus
    for (int k = 0; k < KK; ++k)
        lam[k] = 0.025 + 0.95 * (1.0 / (1.0 + (double)expf(-uld[k])));

    for (int k = 0; k < KK; ++k) {
        double wdt = kx[k + 1] - kx[k];
        double hgt = ky[k + 1] - ky[k];
        double d0 = der[k], d1 = der[k + 1], l = lam[k];
        double delta = hgt / wdt;
        double wb = sqrt(d0 / d1);                       // wa = 1
        double wc = (l * d0 + (1.0 - l) * wb * d1) / delta;
        double ya = ky[k], yb = ky[k] + hgt;
        double wcyc = wc * (((1.0 - l) * ya + l * wb * yb) / ((1.0 - l) + l * wb));
        double wbyb = wb * yb;
        double invw = 1.0 / wdt, icw = kx[k];

        // left sub-bin (theta <= l):  num = ya*l + (wcyc-ya)*th ; den = l + (wc-1)*th
        {
            double A = ya * l, P = wcyc - ya, C = l, Q = wc - 1.0;
            double Bp = P * invw, Dp = Q * invw;
            parG[d * 16 + 2 * k] = make_float4((float)(A - Bp * icw), (float)Bp,
                                               (float)(C - Dp * icw), (float)Dp);
        }
        // right sub-bin: num = (wcyc - wbyb*l) + (wbyb-wcyc)*th ; den = (wc - wb*l) + (wb-wc)*th
        {
            double A = wcyc - wbyb * l, P = wbyb - wcyc, C = wc - wb * l, Q = wb - wc;
            double Bp = P * invw, Dp = Q * invw;
            parG[d * 16 + 2 * k + 1] = make_float4((float)(A - Bp * icw), (float)Bp,
                                                   (float)(C - Dp * icw), (float)Dp);
        }
        // boundaries: s[2k]=kx[k], s[2k+1]=kx[k]+l*wdt ; store s[1..15] at [i-1]
        if (k > 0) bndG[d * 15 + (2 * k - 1)] = (float)kx[k];
        bndG[d * 15 + (2 * k)]     = (float)(kx[k] + l * wdt);
    }
}

// ---------------------------------------------------------------------------
// Main kernel. lane -> one d-column; 15 boundaries in VGPRs (loaded from
// global; no s_bnd in LDS -> 17408 B -> 8 blocks/CU). Prefetch depth 4
// (cur/nxt) keeps VGPR <= 64 so __launch_bounds__(256,8) holds WITHOUT
// scratch spills (R2 measured 36 VGPR with this shape); 32 waves/CU TLP does
// the latency hiding. Grid = 2048 blocks = exactly 8/CU * 256 CU: one full
// residency wave, no tail.
// Bank-conflict fix: par slot rotated by (lane>>3) so the 8 lanes sharing a
// mod-8 bank class spread across bank groups even when their data-dependent
// bin indices j coincide (R2: 2.13M conflicts without this).
// ---------------------------------------------------------------------------
__global__ __launch_bounds__(256, 8)
void spline_main(const float* __restrict__ x, const float4* __restrict__ parG,
                 const float* __restrict__ bndG, float* __restrict__ out, int B) {
    __shared__ float4 s_par[DTILE * 17];   // stride 17 float4; slot 16 is pad

    const int tid = threadIdx.x;
    const int dbase = blockIdx.x * DTILE;
    const int lane = tid & 63;
    const int w    = tid >> 6;
    const int d    = dbase + lane;

    const size_t rowbase = (size_t)(blockIdx.y * ROWS + w * 32) * DD + d;
    const float* xp = x + rowbase;
    float*       op = out + rowbase;

    // issue the first x-load quad before anything else (overlaps staging)
    float cur[4], nxt[4];
#pragma unroll
    for (int r = 0; r < 4; ++r) cur[r] = xp[(size_t)r * DD];

    // boundary loads (independent of LDS staging)
    const float* bp = bndG + (size_t)d * 15;
    const float b1 = bp[0],  b2 = bp[1],  b3 = bp[2],  b4 = bp[3];
    const float b5 = bp[4],  b6 = bp[5],  b7 = bp[6],  b8 = bp[7];
    const float b9 = bp[8],  b10 = bp[9], b11 = bp[10], b12 = bp[11];
    const float b13 = bp[12], b14 = bp[13], b15 = bp[14];

    for (int i = tid; i < DTILE * 16; i += 256) {
        int ld = i >> 4, v = i & 15;
        s_par[ld * 17 + ((v + (ld >> 3)) & 15)] = parG[(size_t)(dbase + ld) * 16 + v];
    }
    __syncthreads();

    const int pb  = lane * 17;
    const int rot = lane >> 3;

#pragma unroll 1
    for (int g = 0; g < 8; ++g) {
        if (g < 7) {
#pragma unroll
            for (int r = 0; r < 4; ++r) nxt[r] = xp[(size_t)((g + 1) * 4 + r) * DD];
        }
#pragma unroll
        for (int r = 0; r < 4; ++r) {
            const float xo = cur[r];
            const float xc = __builtin_amdgcn_fmed3f(xo, -3.0f, 3.0f);
            // 4-level branchless binary search over registers
            const bool c3 = xc >= b8;
            const float m2 = c3 ? b12 : b4;
            const bool c2 = xc >= m2;
            const float m1 = c3 ? (c2 ? b14 : b10) : (c2 ? b6 : b2);
            const bool c1 = xc >= m1;
            const float t01 = c1 ? b3  : b1;
            const float t23 = c1 ? b7  : b5;
            const float t45 = c1 ? b11 : b9;
            const float t67 = c1 ? b15 : b13;
            const float m0 = c3 ? (c2 ? t67 : t45) : (c2 ? t23 : t01);
            const bool c0 = xc >= m0;
            const int j = (c3 ? 8 : 0) + (c2 ? 4 : 0) + (c1 ? 2 : 0) + (c0 ? 1 : 0);

            const float4 p = s_par[pb + ((j + rot) & 15)];
            const float num = fmaf(p.y, xc, p.x);
            const float den = fmaf(p.w, xc, p.z);
            const float res = __fdividef(num, den);
            const float val = (xo == xc) ? res : xo;   // outside [-3,3] -> identity
            __builtin_nontemporal_store(val, &op[(size_t)(g * 4 + r) * DD]);
        }
#pragma unroll
        for (int r = 0; r < 4; ++r) cur[r] = nxt[r];
    }
}

extern "C" void kernel_launch(void* const* d_in, const int* in_sizes, int n_in,
                              void* d_out, int out_size, void* d_ws, size_t ws_size,
                              hipStream_t stream) {
    const float* x  = (const float*)d_in[0];
    const float* uw = (const float*)d_in[1];
    const float* uh = (const float*)d_in[2];
    const float* ud = (const float*)d_in[3];
    const float* ul = (const float*)d_in[4];
    float* outp = (float*)d_out;

    const int B = in_sizes[0] / DD;   // 65536

    float4* parG = (float4*)d_ws;                                  // 256*16*16 = 64 KiB
    float*  bndG = (float*)((char*)d_ws + (size_t)DD * 16 * sizeof(float4)); // +15 KiB

    spline_setup<<<dim3((DD + 63) / 64), dim3(64), 0, stream>>>(uw, uh, ud, ul, parG, bndG);
    spline_main<<<dim3(DD / DTILE, B / ROWS), dim3(256), 0, stream>>>(x, parG, bndG, outp, B);
}

// Round 5
// 126.023 us; speedup vs baseline: 1.0634x; 1.0322x over previous
//
#include <hip/hip_runtime.h>
#include <math.h>

// Problem constants (from setup_inputs): x[B,D] fp32, K=8 bins per column.
#define DD   256
#define KK   8
#define DTILE 64      // d-columns per block
#define ROWS  128     // b-rows per block (32 per wave)

// ---------------------------------------------------------------------------
// Setup kernel, v2: 8 lanes per column d (2048 threads total). R4 profiling
// showed the v1 one-thread-per-d version took 43 us: fp64 arrays kx/ky/der
// spilled to scratch (VGPR=64) and 4 lonely waves serialized on scratch
// latency. v2 keeps everything in scalars: width-8 shfl_xor for softmax
// max/sum, width-8 shfl_up scan for the knot cumsum, lane k emits bin k's
// two Mobius coefficient quads. No arrays -> no spills.
//
// Per sub-bin j in [0,16):  out(x) = (A' + B'x)/(C' + D'x) for x in [s_j,s_{j+1})
// sub-bin 2k = theta in [0,lam_k], 2k+1 = theta in [lam_k,1]; coefficients
// composed in double to kill cancellation from the 1/width fold.
// parG: float4[D*16]; bndG: float[D*15] interior boundaries s[1..15].
// ---------------------------------------------------------------------------
__global__ __launch_bounds__(256)
void spline_setup(const float* __restrict__ uw, const float* __restrict__ uh,
                  const float* __restrict__ ud, const float* __restrict__ ul,
                  float4* __restrict__ parG, float* __restrict__ bndG) {
    const int t = blockIdx.x * blockDim.x + threadIdx.x;   // 0..2047
    const int d = t >> 3;
    const int k = t & 7;
    if (d >= DD) return;

    const float uwv = uw[d * KK + k];
    const float uhv = uh[d * KK + k];
    const float ulv = ul[d * KK + k];

    // group-of-8 softmax max (exact) then sum in double (reassociation-safe)
    float mw = uwv, mh = uhv;
    for (int off = 1; off < 8; off <<= 1) {
        mw = fmaxf(mw, __shfl_xor(mw, off, 8));
        mh = fmaxf(mh, __shfl_xor(mh, off, 8));
    }
    const float ew = expf(uwv - mw), eh = expf(uhv - mh);
    double sw = (double)ew, sh = (double)eh;
    for (int off = 1; off < 8; off <<= 1) {
        sw += __shfl_xor(sw, off, 8);
        sh += __shfl_xor(sh, off, 8);
    }
    const double wk = 1e-3 + (1.0 - 1e-3 * KK) * ((double)ew / sw);
    const double hk = 1e-3 + (1.0 - 1e-3 * KK) * ((double)eh / sh);

    // inclusive scan over the 8 lanes of this column -> cumulative widths/heights
    double cw = wk, ch = hk;
    for (int off = 1; off < 8; off <<= 1) {
        const double aw = __shfl_up(cw, (unsigned)off, 8);
        const double ah = __shfl_up(ch, (unsigned)off, 8);
        if (k >= off) { cw += aw; ch += ah; }
    }

    // knots (reference forces the endpoints to +/-bound before diffing)
    const double kxlo = (k == 0) ? -3.0 : 6.0 * (cw - wk) - 3.0;
    const double kxhi = (k == 7) ?  3.0 : 6.0 * cw - 3.0;
    const double kylo = (k == 0) ? -3.0 : 6.0 * (ch - hk) - 3.0;
    const double kyhi = (k == 7) ?  3.0 : 6.0 * ch - 3.0;

    // derivatives (pad value 1-MIN_DERIV at both ends), lambda
    const double d0 = (k == 0) ? (1.0 - 1e-3)
                               : (1e-3 + (double)log1pf(expf(ud[d * (KK - 1) + k - 1])));
    const double d1 = (k == 7) ? (1.0 - 1e-3)
                               : (1e-3 + (double)log1pf(expf(ud[d * (KK - 1) + k])));
    const double l = 0.025 + 0.95 * (1.0 / (1.0 + (double)expf(-ulv)));

    const double wdt = kxhi - kxlo;
    const double hgt = kyhi - kylo;
    const double delta = hgt / wdt;
    const double wb = sqrt(d0 / d1);                       // wa = 1
    const double wc = (l * d0 + (1.0 - l) * wb * d1) / delta;
    const double ya = kylo, yb = kyhi;
    const double wcyc = wc * (((1.0 - l) * ya + l * wb * yb) / ((1.0 - l) + l * wb));
    const double wbyb = wb * yb;
    const double invw = 1.0 / wdt, icw = kxlo;

    // left sub-bin (theta <= l): num = ya*l + (wcyc-ya)*th ; den = l + (wc-1)*th
    {
        const double A = ya * l, P = wcyc - ya, C = l, Q = wc - 1.0;
        const double Bp = P * invw, Dp = Q * invw;
        parG[d * 16 + 2 * k] = make_float4((float)(A - Bp * icw), (float)Bp,
                                           (float)(C - Dp * icw), (float)Dp);
    }
    // right sub-bin: num = (wcyc - wbyb*l) + (wbyb-wcyc)*th ; den = (wc - wb*l) + (wb-wc)*th
    {
        const double A = wcyc - wbyb * l, P = wbyb - wcyc, C = wc - wb * l, Q = wb - wc;
        const double Bp = P * invw, Dp = Q * invw;
        parG[d * 16 + 2 * k + 1] = make_float4((float)(A - Bp * icw), (float)Bp,
                                               (float)(C - Dp * icw), (float)Dp);
    }
    // boundaries: s[2k]=kxlo (k>0), s[2k+1]=kxlo + l*wdt ; s[i] stored at [i-1]
    if (k > 0) bndG[d * 15 + (2 * k - 1)] = (float)kxlo;
    bndG[d * 15 + (2 * k)] = (float)(kxlo + l * wdt);
}

// ---------------------------------------------------------------------------
// Main kernel. lane -> one d-column; 15 boundaries in VGPRs (loaded from
// global; no s_bnd in LDS -> 17408 B -> 8 blocks/CU). Prefetch depth 4
// (cur/nxt) keeps VGPR <= 64 so __launch_bounds__(256,8) holds without
// scratch spills; 32 waves/CU TLP does the latency hiding. Grid = 2048
// blocks = exactly 8/CU * 256 CU: one full residency wave, no tail.
// Bank-conflict fix: par slot rotated by (lane>>3) so the 8 lanes sharing a
// mod-8 bank class spread across bank groups even when their data-dependent
// bin indices j coincide (R2: 2.13M conflicts without this).
// ---------------------------------------------------------------------------
__global__ __launch_bounds__(256, 8)
void spline_main(const float* __restrict__ x, const float4* __restrict__ parG,
                 const float* __restrict__ bndG, float* __restrict__ out, int B) {
    __shared__ float4 s_par[DTILE * 17];   // stride 17 float4; slot 16 is pad

    const int tid = threadIdx.x;
    const int dbase = blockIdx.x * DTILE;
    const int lane = tid & 63;
    const int w    = tid >> 6;
    const int d    = dbase + lane;

    const size_t rowbase = (size_t)(blockIdx.y * ROWS + w * 32) * DD + d;
    const float* xp = x + rowbase;
    float*       op = out + rowbase;

    // issue the first x-load quad before anything else (overlaps staging)
    float cur[4], nxt[4];
#pragma unroll
    for (int r = 0; r < 4; ++r) cur[r] = xp[(size_t)r * DD];

    // boundary loads (independent of LDS staging)
    const float* bp = bndG + (size_t)d * 15;
    const float b1 = bp[0],  b2 = bp[1],  b3 = bp[2],  b4 = bp[3];
    const float b5 = bp[4],  b6 = bp[5],  b7 = bp[6],  b8 = bp[7];
    const float b9 = bp[8],  b10 = bp[9], b11 = bp[10], b12 = bp[11];
    const float b13 = bp[12], b14 = bp[13], b15 = bp[14];

    for (int i = tid; i < DTILE * 16; i += 256) {
        int ld = i >> 4, v = i & 15;
        s_par[ld * 17 + ((v + (ld >> 3)) & 15)] = parG[(size_t)(dbase + ld) * 16 + v];
    }
    __syncthreads();

    const int pb  = lane * 17;
    const int rot = lane >> 3;

#pragma unroll 1
    for (int g = 0; g < 8; ++g) {
        if (g < 7) {
#pragma unroll
            for (int r = 0; r < 4; ++r) nxt[r] = xp[(size_t)((g + 1) * 4 + r) * DD];
        }
#pragma unroll
        for (int r = 0; r < 4; ++r) {
            const float xo = cur[r];
            const float xc = __builtin_amdgcn_fmed3f(xo, -3.0f, 3.0f);
            // 4-level branchless binary search over registers
            const bool c3 = xc >= b8;
            const float m2 = c3 ? b12 : b4;
            const bool c2 = xc >= m2;
            const float m1 = c3 ? (c2 ? b14 : b10) : (c2 ? b6 : b2);
            const bool c1 = xc >= m1;
            const float t01 = c1 ? b3  : b1;
            const float t23 = c1 ? b7  : b5;
            const float t45 = c1 ? b11 : b9;
            const float t67 = c1 ? b15 : b13;
            const float m0 = c3 ? (c2 ? t67 : t45) : (c2 ? t23 : t01);
            const bool c0 = xc >= m0;
            const int j = (c3 ? 8 : 0) + (c2 ? 4 : 0) + (c1 ? 2 : 0) + (c0 ? 1 : 0);

            const float4 p = s_par[pb + ((j + rot) & 15)];
            const float num = fmaf(p.y, xc, p.x);
            const float den = fmaf(p.w, xc, p.z);
            const float res = __fdividef(num, den);
            const float val = (xo == xc) ? res : xo;   // outside [-3,3] -> identity
            __builtin_nontemporal_store(val, &op[(size_t)(g * 4 + r) * DD]);
        }
#pragma unroll
        for (int r = 0; r < 4; ++r) cur[r] = nxt[r];
    }
}

extern "C" void kernel_launch(void* const* d_in, const int* in_sizes, int n_in,
                              void* d_out, int out_size, void* d_ws, size_t ws_size,
                              hipStream_t stream) {
    const float* x  = (const float*)d_in[0];
    const float* uw = (const float*)d_in[1];
    const float* uh = (const float*)d_in[2];
    const float* ud = (const float*)d_in[3];
    const float* ul = (const float*)d_in[4];
    float* outp = (float*)d_out;

    const int B = in_sizes[0] / DD;   // 65536

    float4* parG = (float4*)d_ws;                                  // 256*16*16 = 64 KiB
    float*  bndG = (float*)((char*)d_ws + (size_t)DD * 16 * sizeof(float4)); // +15 KiB

    spline_setup<<<dim3((DD * KK + 255) / 256), dim3(256), 0, stream>>>(uw, uh, ud, ul, parG, bndG);
    spline_main<<<dim3(DD / DTILE, B / ROWS), dim3(256), 0, stream>>>(x, parG, bndG, outp, B);
}